// Round 11
// baseline (25475.447 us; speedup 1.0000x reference)
//
#include <hip/hip_runtime.h>
#include <math.h>

#define Vc 50257
#define NEG_INF (-__builtin_inff())
#define VCOLS 512
#define NVB 99      // 99*512 = 50688 >= 50257
#define NBB 32      // 4 blocks/batch, 16 rows each, 1 row/wave
#define GUARD (1 << 19)

// ---- int workspace (first 64 KB, memset 0):
//   AF[64] @0, CF[64] @64, mbV[99][32] @256, mbL[131][32] @4096
// ---- float workspace offsets:
#define F_WV   16384   // [8][64]
#define F_MS   16896   // [8][2]
#define F_X2   16960   // [8][64]
#define F_SM   17472   // [8][128]
#define F_SS   18496   // [8][128]
#define F_SI   19520   // [8][128] int
#define F_IG   20544   // [8] int
#define F_K2G  24576   // [8][64][64]
#define F_V2G  57344   // [8][64][64]

__device__ __forceinline__ float wsum64(float v) {
#pragma unroll
  for (int m = 32; m >= 1; m >>= 1) v += __shfl_xor(v, m, 64);
  return v;
}

__device__ __forceinline__ float red8(float v) {
  v += __shfl_xor(v, 1, 64);
  v += __shfl_xor(v, 2, 64);
  v += __shfl_xor(v, 4, 64);
  return v;
}

__device__ __forceinline__ float proj_lds(float xv, float* xb,
                                          const float* W,
                                          const float* __restrict__ bias, int lane) {
  xb[lane] = xv;
  asm volatile("s_waitcnt lgkmcnt(0)" ::: "memory");
  float acc = bias[lane];
  const float4* x4 = (const float4*)xb;
#pragma unroll
  for (int i = 0; i < 16; ++i) {
    float4 xc = x4[i];
    acc = fmaf(xc.x, W[(4 * i + 0) * 64 + lane], acc);
    acc = fmaf(xc.y, W[(4 * i + 1) * 64 + lane], acc);
    acc = fmaf(xc.z, W[(4 * i + 2) * 64 + lane], acc);
    acc = fmaf(xc.w, W[(4 * i + 3) * 64 + lane], acc);
  }
  asm volatile("" ::: "memory");
  return acc;
}

__device__ __forceinline__ float ln64(float xv, const float* __restrict__ g,
                                      const float* __restrict__ b, int lane) {
  float mean = wsum64(xv) * 0.015625f;
  float d = xv - mean;
  float var = wsum64(d * d) * 0.015625f;
  float r = 1.0f / sqrtf(var + 1e-5f);
  return d * r * g[lane] + b[lane];
}

__device__ __forceinline__ float cloadf(const float* p) {
  return __hip_atomic_load(p, __ATOMIC_RELAXED, __HIP_MEMORY_SCOPE_AGENT);
}
__device__ __forceinline__ int cloadi(const int* p) {
  return __hip_atomic_load(p, __ATOMIC_RELAXED, __HIP_MEMORY_SCOPE_AGENT);
}
__device__ __forceinline__ void cstoref(float* p, float v) {
  __hip_atomic_store(p, v, __ATOMIC_RELAXED, __HIP_MEMORY_SCOPE_AGENT);
}
__device__ __forceinline__ void cstorei(int* p, int v) {
  __hip_atomic_store(p, v, __ATOMIC_RELAXED, __HIP_MEMORY_SCOPE_AGENT);
}

__device__ __forceinline__ void fma_burst(float& d0, float& d1, float& d2, float& d3) {
#pragma unroll
  for (int i = 0; i < 16; ++i) {
    d0 = fmaf(d0, 1.0000001f, 1.0f);
    d1 = fmaf(d1, 1.0000002f, 1.0f);
    d2 = fmaf(d2, 1.0000003f, 1.0f);
    d3 = fmaf(d3, 1.0000004f, 1.0f);
  }
}

// Whole-block wait on a private mailbox (monotone step token). Wave 0 is the sole
// memory poller; other waves spin on an LDS release word. Bounded (no GPU hang).
__device__ __forceinline__ void block_wait(int* mbox, int target, int* lrel, int tok,
                                           int wvid, int lane) {
  float d0 = 0.f, d1 = 0.f, d2 = 0.f, d3 = 0.f;
  int guard = GUARD;
  if (wvid == 0) {
    while (__hip_atomic_load(mbox, __ATOMIC_RELAXED, __HIP_MEMORY_SCOPE_AGENT) < target) {
      fma_burst(d0, d1, d2, d3);
      if (--guard == 0) break;
    }
    __builtin_amdgcn_s_waitcnt(0);
    if (lane == 0)
      __hip_atomic_store(lrel, tok, __ATOMIC_RELAXED, __HIP_MEMORY_SCOPE_WORKGROUP);
  } else {
    while (__hip_atomic_load(lrel, __ATOMIC_RELAXED, __HIP_MEMORY_SCOPE_WORKGROUP) < tok) {
      fma_burst(d0, d1, d2, d3);
      if (--guard == 0) break;
    }
  }
  asm volatile("" :: "v"(d0), "v"(d1), "v"(d2), "v"(d3));
  __syncthreads();
}

struct LayerR {
  const float *saW3, *sab3, *caW0, *cab0, *caW3, *cab3,
              *ffW1, *ffb1, *ffW2, *ffb2, *g0, *be0, *g1, *be1, *g2, *be2;
  float cs1_r, cs2_r, cab1_r, cab2_r;
};

__device__ __forceinline__ void build_layer_s(LayerR& L, const float* sWl, int n, int lane,
    const float* sa_b, const float* ca_b,
    const float* ff_W1, const float* ff_b1, const float* ff_W2, const float* ff_b2,
    const float* ln_g, const float* ln_b, float cs1, float cs2) {
  L.saW3 = sWl;              L.sab3 = sa_b + (n * 4 + 3) * 64;
  L.caW0 = sWl + 4096;       L.cab0 = ca_b + (n * 4 + 0) * 64;
  L.caW3 = sWl + 2 * 4096;   L.cab3 = ca_b + (n * 4 + 3) * 64;
  L.ffW1 = ff_W1 + n * 4096; L.ffb1 = ff_b1 + n * 64;
  L.ffW2 = ff_W2 + n * 4096; L.ffb2 = ff_b2 + n * 64;
  L.g0 = ln_g + (n * 3 + 0) * 64;  L.be0 = ln_b + (n * 3 + 0) * 64;
  L.g1 = ln_g + (n * 3 + 1) * 64;  L.be1 = ln_b + (n * 3 + 1) * 64;
  L.g2 = ln_g + (n * 3 + 2) * 64;  L.be2 = ln_b + (n * 3 + 2) * 64;
  L.cab1_r = ca_b[(n * 4 + 1) * 64 + lane];
  L.cab2_r = ca_b[(n * 4 + 2) * 64 + lane];
  L.cs1_r = cs1; L.cs2_r = cs2;
}

__device__ __forceinline__ void build_layer_g(LayerR& L, int n, int lane,
    const float* sa_W, const float* sa_b, const float* ca_W, const float* ca_b,
    const float* ff_W1, const float* ff_b1, const float* ff_W2, const float* ff_b2,
    const float* ln_g, const float* ln_b, float cs1, float cs2) {
  L.saW3 = sa_W + (n * 4 + 3) * 4096; L.sab3 = sa_b + (n * 4 + 3) * 64;
  L.caW0 = ca_W + (n * 4 + 0) * 4096; L.cab0 = ca_b + (n * 4 + 0) * 64;
  L.caW3 = ca_W + (n * 4 + 3) * 4096; L.cab3 = ca_b + (n * 4 + 3) * 64;
  L.ffW1 = ff_W1 + n * 4096;          L.ffb1 = ff_b1 + n * 64;
  L.ffW2 = ff_W2 + n * 4096;          L.ffb2 = ff_b2 + n * 64;
  L.g0 = ln_g + (n * 3 + 0) * 64;     L.be0 = ln_b + (n * 3 + 0) * 64;
  L.g1 = ln_g + (n * 3 + 1) * 64;     L.be1 = ln_b + (n * 3 + 1) * 64;
  L.g2 = ln_g + (n * 3 + 2) * 64;     L.be2 = ln_b + (n * 3 + 2) * 64;
  L.cab1_r = ca_b[(n * 4 + 1) * 64 + lane];
  L.cab2_r = ca_b[(n * 4 + 2) * 64 + lane];
  L.cs1_r = cs1; L.cs2_r = cs2;
}

// One wave, one row. K/V row stride ks (65 = padded LDS, 64 = ws global).
__device__ float transformer_row(int lane, int t, float x, float q,
                                 const float* Kb, const float* Vb, int ks,
                                 const float* wv, float* xb, float* pb,
                                 const LayerR& P) {
  const float ISQ8 = 0.35355339059327373f;  // 1/sqrt(8)
  xb[lane] = q;
  asm volatile("s_waitcnt lgkmcnt(0)" ::: "memory");
  float a[8] = {0.f, 0.f, 0.f, 0.f, 0.f, 0.f, 0.f, 0.f};
  const float* Krow = Kb + lane * ks;
  const float4* xq4 = (const float4*)xb;
#pragma unroll
  for (int i = 0; i < 16; ++i) {
    float4 xc = xq4[i];
    a[i >> 1] = fmaf(xc.x, Krow[4 * i + 0], a[i >> 1]);
    a[i >> 1] = fmaf(xc.y, Krow[4 * i + 1], a[i >> 1]);
    a[i >> 1] = fmaf(xc.z, Krow[4 * i + 2], a[i >> 1]);
    a[i >> 1] = fmaf(xc.w, Krow[4 * i + 3], a[i >> 1]);
  }
  const bool act = lane < t;
  float m[8];
#pragma unroll
  for (int h = 0; h < 8; ++h) { a[h] = act ? a[h] * ISQ8 : NEG_INF; m[h] = a[h]; }
#pragma unroll
  for (int msk = 1; msk < 64; msk <<= 1) {
#pragma unroll
    for (int h = 0; h < 8; ++h) m[h] = fmaxf(m[h], __shfl_xor(m[h], msk, 64));
  }
  float l[8];
#pragma unroll
  for (int h = 0; h < 8; ++h) { a[h] = act ? expf(a[h] - m[h]) : 0.f; l[h] = a[h]; }
#pragma unroll
  for (int msk = 1; msk < 64; msk <<= 1) {
#pragma unroll
    for (int h = 0; h < 8; ++h) l[h] += __shfl_xor(l[h], msk, 64);
  }
#pragma unroll
  for (int h = 0; h < 8; ++h) pb[h * 64 + lane] = a[h] / l[h];
  asm volatile("s_waitcnt lgkmcnt(0)" ::: "memory");
  const float* pr = pb + (lane >> 3) * 64;
  float attn = 0.f;
  for (int k = 0; k < t; ++k) attn = fmaf(pr[k], Vb[k * ks + lane], attn);

  float y1 = ln64(x + proj_lds(attn, xb, P.saW3, P.sab3, lane), P.g0, P.be0, lane);
  float qc = proj_lds(y1, xb, P.caW0, P.cab0, lane);
  float pa = red8(qc * P.cs1_r);
  float pc = red8(qc * P.cab1_r);
  const float4* wv4 = (const float4*)wv;
  float mc = NEG_INF;
#pragma unroll
  for (int i = 0; i < 16; ++i) {
    float4 wq = wv4[i];
    int k = 4 * i;
    if (k + 0 < t) mc = fmaxf(mc, fmaf(pa, wq.x, pc));
    if (k + 1 < t) mc = fmaxf(mc, fmaf(pa, wq.y, pc));
    if (k + 2 < t) mc = fmaxf(mc, fmaf(pa, wq.z, pc));
    if (k + 3 < t) mc = fmaxf(mc, fmaf(pa, wq.w, pc));
  }
  float lc = 0.f, z = 0.f;
#pragma unroll
  for (int i = 0; i < 16; ++i) {
    float4 wq = wv4[i];
    int k = 4 * i;
    float wk[4] = {wq.x, wq.y, wq.z, wq.w};
#pragma unroll
    for (int j = 0; j < 4; ++j) {
      if (k + j < t) {
        float raw = fmaf(pa, wk[j], pc);
        float pw = expf((raw - mc) * ISQ8);
        lc += pw;
        z = fmaf(pw, wk[j], z);
      }
    }
  }
  float oc = fmaf(z / lc, P.cs2_r, P.cab2_r);
  float y2 = ln64(y1 + proj_lds(oc, xb, P.caW3, P.cab3, lane), P.g1, P.be1, lane);
  float f = fmaxf(proj_lds(y2, xb, P.ffW1, P.ffb1, lane), 0.f);
  float y3 = ln64(y2 + proj_lds(f, xb, P.ffW2, P.ffb2, lane), P.g2, P.be2, lane);
  return y3;
}

__global__ __launch_bounds__(1024) void gen_kernel(
    const float* __restrict__ noise, const float* __restrict__ lin_W,
    const float* __restrict__ lin_b, const float* __restrict__ sa_W,
    const float* __restrict__ sa_b, const float* __restrict__ ca_W,
    const float* __restrict__ ca_b, const float* __restrict__ ff_W1,
    const float* __restrict__ ff_b1, const float* __restrict__ ff_W2,
    const float* __restrict__ ff_b2, const float* __restrict__ ln_g,
    const float* __restrict__ ln_b, const float* __restrict__ emb,
    const float* __restrict__ soft_W, const float* __restrict__ soft_b,
    const int* __restrict__ start_id, float* __restrict__ dout,
    float* __restrict__ wsf) {
  const int tid = threadIdx.x, lane = tid & 63, wvid = tid >> 6;
  const int bid = blockIdx.x;
  int* wsi = (int*)wsf;
  int* AF  = wsi;          // [64] layer-1 arrivals, target 32
  int* CF  = wsi + 64;     // [64] vocab arrivals, target 99
  int* mbV = wsi + 256;    // [99][32] private mailboxes (l1 outputs ready)
  int* mbL = wsi + 4096;   // [131][32] private mailboxes (argmax/MS ready)
  int* IG  = (int*)(wsf + F_IG);

  __shared__ float lds[38832];   // 155328 B

  if (bid < NBB) {
    // ================= layer-1 block: batch b, rows sb2*16..sb2*16+15 =================
    const int b = bid >> 2, sb2 = bid & 3;
    float* sW   = lds;             // 3 x 4096: saW3(n0), caW0(n0), caW3(n0)
    float* K1l  = lds + 12288;     // 63 rows stride 65, persistent KV cache
    float* V1l  = lds + 16384;
    float* wvl  = lds + 20480;
    float* ynew = lds + 20544;
    float* qnew = lds + 20608;
    float* xbuf = lds + 20672;     // 16 x 64
    float* pbuf = lds + 21696;     // 16 x 512
    int* lrel   = (int*)(lds + 29888);
    float* myxb = xbuf + wvid * 64;
    float* mypb = pbuf + wvid * 512;
    if (tid == 0) *lrel = 0;

    // ---- startup: cs (layer 0) ----
    if (wvid == 0) {
      float c1 = 0.f, c2 = 0.f;
      for (int e = 0; e < 64; ++e) {
        c1 += ca_W[1 * 4096 + e * 64 + lane];
        c2 += ca_W[2 * 4096 + e * 64 + lane];
      }
      ynew[lane] = c1; qnew[lane] = c2;
    }
    __syncthreads();
    const float cs1 = ynew[lane], cs2 = qnew[lane];
    __syncthreads();
    // ---- stage layer-0 weights into LDS (once) ----
    float4* dd = (float4*)sW;
    dd[tid]        = ((const float4*)(sa_W + 3 * 4096))[tid];
    dd[1024 + tid] = ((const float4*)(ca_W))[tid];
    dd[2048 + tid] = ((const float4*)(ca_W + 3 * 4096))[tid];
    // ---- wv + seed row 0 ----
    float x_r = 0.f, q_r = 0.f;
    if (wvid == 0) {
      float nz = noise[b * 64 + lane];
      float t1 = proj_lds(nz, myxb, lin_W, lin_b, lane);
      float wvr = proj_lds(t1, myxb, lin_W + 4096, lin_b + 64, lane);
      wvl[lane] = wvr;
      if (sb2 == 0) cstoref(wsf + F_WV + b * 64 + lane, wvr);
      float y0 = emb[start_id[0] * 64 + lane] + ((lane & 1) ? 1.0f : 0.0f);
      float q0 = proj_lds(y0, myxb, sa_W, sa_b, lane);
      float k0 = proj_lds(y0, myxb, sa_W + 4096, sa_b + 64, lane);
      float v0 = proj_lds(y0, myxb, sa_W + 2 * 4096, sa_b + 128, lane);
      K1l[lane] = k0; V1l[lane] = v0;
      ynew[lane] = y0; qnew[lane] = q0;
      __builtin_amdgcn_s_waitcnt(0);   // drain F_WV store before first AF post
    }
    __syncthreads();
    if (sb2 == 0 && wvid == 0) { x_r = ynew[lane]; q_r = qnew[lane]; }
    LayerR L0;
    build_layer_s(L0, sW, 0, lane, sa_b, ca_b, ff_W1, ff_b1, ff_W2, ff_b2,
                  ln_g, ln_b, cs1, cs2);

    for (int t = 1; t <= 63; ++t) {
      if (t >= 2) {
        float pev = 0.f;
        if (wvid == 0) {  // pe[t-1], argmax-independent: compute before the wait
          double ang = (double)(t - 1) / pow(10000.0, (double)(lane & 62) / 64.0);
          pev = (lane & 1) ? (float)cos(ang) : (float)sin(ang);
        }
        block_wait(mbL + bid * 32, t - 1, lrel, t - 1, wvid, lane);
        if (wvid == 0) {   // build row t-1 (redundant per block; append to LDS KV)
          int ig = cloadi(IG + b);
          float y = emb[ig * 64 + lane] + pev;
          float qn = proj_lds(y, myxb, sa_W, sa_b, lane);
          float kn = proj_lds(y, myxb, sa_W + 4096, sa_b + 64, lane);
          float vn = proj_lds(y, myxb, sa_W + 2 * 4096, sa_b + 128, lane);
          K1l[(t - 1) * 65 + lane] = kn;
          V1l[(t - 1) * 65 + lane] = vn;
          ynew[lane] = y; qnew[lane] = qn;
        }
        __syncthreads();
        if (sb2 == ((t - 1) >> 4) && wvid == ((t - 1) & 15)) {
          x_r = ynew[lane]; q_r = qnew[lane];
        }
      }
      const int row = sb2 * 16 + wvid;
      if (row < t) {
        float out = transformer_row(lane, t, x_r, q_r, K1l, V1l, 65, wvl, myxb, mypb, L0);
        float k2 = proj_lds(out, myxb, sa_W + 5 * 4096, sa_b + 5 * 64, lane);
        float v2 = proj_lds(out, myxb, sa_W + 6 * 4096, sa_b + 6 * 64, lane);
        cstoref(wsf + F_K2G + b * 4096 + row * 64 + lane, k2);
        cstoref(wsf + F_V2G + b * 4096 + row * 64 + lane, v2);
        if (row == t - 1) cstoref(wsf + F_X2 + b * 64 + lane, out);
        __builtin_amdgcn_s_waitcnt(0);   // drain my agent stores before counting in
      }
      __syncthreads();
      if (wvid == 0) {
        int old = 0;
        if (lane == 0)
          old = __hip_atomic_fetch_add(&AF[t], 1, __ATOMIC_RELAXED, __HIP_MEMORY_SCOPE_AGENT);
        old = __shfl(old, 0, 64);
        if (old == NBB - 1) {   // detector fans to all vocab mailboxes
          for (int i = lane; i < NVB; i += 64) cstorei(mbV + i * 32, t);
        }
      }
    }
  } else {
    // ================= vocab block: LDS-resident 512-col slice of soft_W =================
    const int jb = bid - NBB;
    const int v = jb * VCOLS + tid;
    const bool valid = (tid < VCOLS) && (v < Vc);
    float* sW2  = lds;                  // (64,512) soft_W slice, staged once
    float* tokf = lds + 32768;          // (8,64)
    float* f2   = lds + 33280;          // (512)
    float* xb8  = lds + 33792;          // 8 x 64
    float* pb8  = lds + 34304;          // 8 x 512
    float* sm   = lds + 38400;          // (16,8)
    int*   si   = (int*)(lds + 38528);
    float* ssm  = lds + 38656;          // (16,8)
    float* bmx  = lds + 38784;          // (8)
    int*   bix  = (int*)(lds + 38792);
    float* msl  = lds + 38800;          // (16)
    int* red    = (int*)(lds + 38816);
    int* lrelV  = (int*)(lds + 38817);
    int* lrelM  = (int*)(lds + 38818);
    float* myxb = xb8 + wvid * 64;      // wvid<8 only
    float* mypb = pb8 + wvid * 512;
    if (tid == 0) { *red = 0; *lrelV = 0; *lrelM = 0; }

    for (int e = 0; e < 64; ++e)
      if (tid < VCOLS) sW2[e * VCOLS + tid] = (v < Vc) ? soft_W[(long)e * Vc + v] : 0.f;
    if (wvid == 0) {   // cs (layer 1) -> f2[0..127] temporarily
      float c1 = 0.f, c2 = 0.f;
      for (int e = 0; e < 64; ++e) {
        c1 += ca_W[5 * 4096 + e * 64 + lane];
        c2 += ca_W[6 * 4096 + e * 64 + lane];
      }
      f2[lane] = c1; f2[64 + lane] = c2;
    }
    __syncthreads();
    const float cs1v = f2[lane], cs2v = f2[64 + lane];
    __syncthreads();
    LayerR L1;
    build_layer_g(L1, 1, lane, sa_W, sa_b, ca_W, ca_b, ff_W1, ff_b1, ff_W2, ff_b2,
                  ln_g, ln_b, cs1v, cs2v);
    const float sbv = valid ? soft_b[v] : 0.f;

    for (int t = 1; t <= 63; ++t) {
      block_wait(mbV + jb * 32, t, lrelV, t, wvid, lane);
      // ---- fused layer-2: wave h = batch h (K2G/V2G/X2 L2-warm) ----
      if (wvid < 8) {
        const int b2 = wvid;
        float x2 = cloadf(wsf + F_X2 + b2 * 64 + lane);
        float q2 = proj_lds(x2, myxb, sa_W + 4 * 4096, sa_b + 4 * 64, lane);
        float tf = transformer_row(lane, t, x2, q2,
                                   wsf + F_K2G + b2 * 4096, wsf + F_V2G + b2 * 4096, 64,
                                   wsf + F_WV + b2 * 64, myxb, mypb, L1);
        tokf[b2 * 64 + lane] = tf;
      }
      __syncthreads();
      if (tid < 512) f2[tid] = tokf[(tid & 7) * 64 + (tid >> 3)];  // f2[e*8+b]
      __syncthreads();
      float lg[8];
#pragma unroll
      for (int b = 0; b < 8; ++b) lg[b] = valid ? sbv : NEG_INF;
      if (valid) {
        const float4* f4 = (const float4*)f2;
        const float* col = sW2 + tid;
#pragma unroll 8
        for (int e = 0; e < 64; ++e) {
          float wc = col[e * VCOLS];
          float4 fa = f4[2 * e], fb = f4[2 * e + 1];
          lg[0] = fmaf(fa.x, wc, lg[0]);
          lg[1] = fmaf(fa.y, wc, lg[1]);
          lg[2] = fmaf(fa.z, wc, lg[2]);
          lg[3] = fmaf(fa.w, wc, lg[3]);
          lg[4] = fmaf(fb.x, wc, lg[4]);
          lg[5] = fmaf(fb.y, wc, lg[5]);
          lg[6] = fmaf(fb.z, wc, lg[6]);
          lg[7] = fmaf(fb.w, wc, lg[7]);
        }
      }
#pragma unroll
      for (int b = 0; b < 8; ++b) {
        float m = lg[b]; int ix = valid ? v : 0x7fffffff;
#pragma unroll
        for (int msk = 1; msk < 64; msk <<= 1) {
          float om = __shfl_xor(m, msk, 64);
          int oi = __shfl_xor(ix, msk, 64);
          if (om > m || (om == m && oi < ix)) { m = om; ix = oi; }
        }
        if (lane == 0) { sm[wvid * 8 + b] = m; si[wvid * 8 + b] = ix; }
      }
      __syncthreads();
      if (tid < 8) {
        float m = NEG_INF; int ix = 0x7fffffff;
        for (int wv = 0; wv < 16; ++wv) {
          float om = sm[wv * 8 + tid]; int oi = si[wv * 8 + tid];
          if (om > m || (om == m && oi < ix)) { m = om; ix = oi; }
        }
        bmx[tid] = m; bix[tid] = ix;
      }
      __syncthreads();
#pragma unroll
      for (int b = 0; b < 8; ++b) {
        float c = valid ? expf(lg[b] - bmx[b]) : 0.f;
        float s = wsum64(c);
        if (lane == 0) ssm[wvid * 8 + b] = s;
      }
      __syncthreads();
      if (wvid == 0) {
        if (lane < 8) {
          float s = 0.f;
          for (int wv = 0; wv < 16; ++wv) s += ssm[wv * 8 + lane];
          cstoref(wsf + F_SM + lane * 128 + jb, bmx[lane]);
          cstoref(wsf + F_SS + lane * 128 + jb, s);
          cstorei((int*)(wsf + F_SI) + lane * 128 + jb, bix[lane]);
        }
        __builtin_amdgcn_s_waitcnt(0);
        if (lane == 0)
          red[0] = __hip_atomic_fetch_add(&CF[t], 1, __ATOMIC_RELAXED, __HIP_MEMORY_SCOPE_AGENT);
      }
      __syncthreads();
      if (red[0] == NVB - 1) {
        // last arriver reduces all 8 batches, writes MS/IG, fans mbL to all blocks
        if (wvid < 8) {
          const int b2 = wvid;
          const float* smp = wsf + F_SM + b2 * 128;
          const float* ssp = wsf + F_SS + b2 * 128;
          const int*   sip = (const int*)(wsf + F_SI) + b2 * 128;
          float mA = cloadf(smp + lane);
          float sA = cloadf(ssp + lane);
          int   iA = cloadi(sip + lane);
          const bool a2 = (64 + lane) < NVB;
          float mB = a2 ? cloadf(smp + 64 + lane) : NEG_INF;
          float sB = a2 ? cloadf(ssp + 64 + lane) : 0.f;
          int   iB = a2 ? cloadi(sip + 64 + lane) : 0x7fffffff;
          float mg = mA; int ig = iA;
          if (mB > mg || (mB == mg && iB < ig)) { mg = mB; ig = iB; }
#pragma unroll
          for (int msk = 1; msk < 64; msk <<= 1) {
            float om = __shfl_xor(mg, msk, 64);
            int oi = __shfl_xor(ig, msk, 64);
            if (om > mg || (om == mg && oi < ig)) { mg = om; ig = oi; }
          }
          float part = sA * expf(mA - mg) + (a2 ? sB * expf(mB - mg) : 0.f);
          float S = wsum64(part);
          if (lane == 0) {
            cstoref(wsf + F_MS + b2 * 2, mg);
            cstoref(wsf + F_MS + b2 * 2 + 1, S);
            cstorei(IG + b2, ig);
          }
          __builtin_amdgcn_s_waitcnt(0);
        }
        __syncthreads();
        for (int i = tid; i < NBB + NVB; i += 1024) cstorei(mbL + i * 32, t);
      }
      block_wait(mbL + (NBB + jb) * 32, t, lrelM, t, wvid, lane);
      if (tid < 16) msl[tid] = cloadf(wsf + F_MS + tid);
      __syncthreads();
      if (valid) {
        long rbase = (long)(t - 1) * Vc + v;
#pragma unroll
        for (int b = 0; b < 8; ++b)
          dout[(long)b * 63 * Vc + rbase] = expf(lg[b] - msl[2 * b]) / msl[2 * b + 1];
      }
    }
  }
}

extern "C" void kernel_launch(void* const* d_in, const int* in_sizes, int n_in,
                              void* d_out, int out_size, void* d_ws, size_t ws_size,
                              hipStream_t stream) {
  (void)in_sizes; (void)n_in; (void)out_size; (void)ws_size;
  hipMemsetAsync(d_ws, 0, 65536, stream);  // zero counters + mailboxes
  gen_kernel<<<dim3(NBB + NVB), dim3(1024), 0, stream>>>(
      (const float*)d_in[0], (const float*)d_in[1], (const float*)d_in[2],
      (const float*)d_in[3], (const float*)d_in[4], (const float*)d_in[5],
      (const float*)d_in[6], (const float*)d_in[7], (const float*)d_in[8],
      (const float*)d_in[9], (const float*)d_in[10], (const float*)d_in[11],
      (const float*)d_in[12], (const float*)d_in[13], (const float*)d_in[14],
      (const float*)d_in[15], (const int*)d_in[16],
      (float*)d_out, (float*)d_ws);
}

// Round 12
// 20606.415 us; speedup vs baseline: 1.2363x; 1.2363x over previous
//
#include <hip/hip_runtime.h>
#include <math.h>

#define Vc 50257
#define NEG_INF (-__builtin_inff())
#define VCOLS 512
#define NVB 99      // 99*512 = 50688 >= 50257
#define NB  8

// ---- workspace float offsets (no flags/atomics; coherence = kernel boundaries) ----
#define WS_PE    0        // [64][64] pe rows (1..62 used)
#define WS_WV    4096     // [8][64]
#define WS_CS    4608     // [2 layers][2][64] column sums of ca_W k/v proj
#define WS_TOKF  4864     // [8][64]
#define WS_MS    5376     // [8][2]
#define WS_SM    8192     // stats_m [8][128]
#define WS_SS    9216     // stats_s [8][128]
#define WS_SI    10240    // stats_i [8][128] (int)
#define WS_X1    16384    // [8][64][64]
#define WS_Q1    49152
#define WS_K1    81920
#define WS_V1    114688   // end 147456 floats (~590 KB)

// ---------------- wave-level helpers ----------------

__device__ __forceinline__ float wsum64(float v) {
#pragma unroll
  for (int m = 32; m >= 1; m >>= 1) v += __shfl_xor(v, m, 64);
  return v;
}

__device__ __forceinline__ float red8(float v) {
  v += __shfl_xor(v, 1, 64);
  v += __shfl_xor(v, 2, 64);
  v += __shfl_xor(v, 4, 64);
  return v;
}

// out[lane] = bias[lane] + sum_e x[e]*W[e*64+lane]; x broadcast via LDS float4 reads.
// W may live in LDS (staged) or global (L2-warm).
__device__ __forceinline__ float proj_lds(float xv, float* xb,
                                          const float* W,
                                          const float* __restrict__ bias, int lane) {
  xb[lane] = xv;
  asm volatile("s_waitcnt lgkmcnt(0)" ::: "memory");
  float acc = bias[lane];
  const float4* x4 = (const float4*)xb;
#pragma unroll
  for (int i = 0; i < 16; ++i) {
    float4 xc = x4[i];
    acc = fmaf(xc.x, W[(4 * i + 0) * 64 + lane], acc);
    acc = fmaf(xc.y, W[(4 * i + 1) * 64 + lane], acc);
    acc = fmaf(xc.z, W[(4 * i + 2) * 64 + lane], acc);
    acc = fmaf(xc.w, W[(4 * i + 3) * 64 + lane], acc);
  }
  asm volatile("" ::: "memory");
  return acc;
}

__device__ __forceinline__ float ln64(float xv, const float* __restrict__ g,
                                      const float* __restrict__ b, int lane) {
  float mean = wsum64(xv) * 0.015625f;
  float d = xv - mean;
  float var = wsum64(d * d) * 0.015625f;
  float r = 1.0f / sqrtf(var + 1e-5f);
  return d * r * g[lane] + b[lane];
}

struct LayerR {
  const float *saW3, *sab3, *caW0, *cab0, *caW3, *cab3,
              *ffW1, *ffb1, *ffW2, *ffb2, *g0, *be0, *g1, *be1, *g2, *be2;
  float cs1_r, cs2_r, cab1_r, cab2_r;
};

// saW3/caW0/caW3 from LDS-staged copies; rest global.
__device__ __forceinline__ void build_layer_s(LayerR& L, int n, int lane,
    const float* sWl, const float* sa_b, const float* ca_b,
    const float* ff_W1, const float* ff_b1, const float* ff_W2, const float* ff_b2,
    const float* ln_g, const float* ln_b, const float* cs_g) {
  L.saW3 = sWl;              L.sab3 = sa_b + (n * 4 + 3) * 64;
  L.caW0 = sWl + 4096;       L.cab0 = ca_b + (n * 4 + 0) * 64;
  L.caW3 = sWl + 2 * 4096;   L.cab3 = ca_b + (n * 4 + 3) * 64;
  L.ffW1 = ff_W1 + n * 4096; L.ffb1 = ff_b1 + n * 64;
  L.ffW2 = ff_W2 + n * 4096; L.ffb2 = ff_b2 + n * 64;
  L.g0 = ln_g + (n * 3 + 0) * 64;  L.be0 = ln_b + (n * 3 + 0) * 64;
  L.g1 = ln_g + (n * 3 + 1) * 64;  L.be1 = ln_b + (n * 3 + 1) * 64;
  L.g2 = ln_g + (n * 3 + 2) * 64;  L.be2 = ln_b + (n * 3 + 2) * 64;
  L.cab1_r = ca_b[(n * 4 + 1) * 64 + lane];
  L.cab2_r = ca_b[(n * 4 + 2) * 64 + lane];
  L.cs1_r = cs_g[(n * 2 + 0) * 64 + lane];
  L.cs2_r = cs_g[(n * 2 + 1) * 64 + lane];
}

// all-global version (weights L2-warm) — used by the fused layer-2
__device__ __forceinline__ void build_layer_g(LayerR& L, int n, int lane,
    const float* sa_W, const float* sa_b, const float* ca_W, const float* ca_b,
    const float* ff_W1, const float* ff_b1, const float* ff_W2, const float* ff_b2,
    const float* ln_g, const float* ln_b, const float* cs_g) {
  L.saW3 = sa_W + (n * 4 + 3) * 4096; L.sab3 = sa_b + (n * 4 + 3) * 64;
  L.caW0 = ca_W + (n * 4 + 0) * 4096; L.cab0 = ca_b + (n * 4 + 0) * 64;
  L.caW3 = ca_W + (n * 4 + 3) * 4096; L.cab3 = ca_b + (n * 4 + 3) * 64;
  L.ffW1 = ff_W1 + n * 4096;          L.ffb1 = ff_b1 + n * 64;
  L.ffW2 = ff_W2 + n * 4096;          L.ffb2 = ff_b2 + n * 64;
  L.g0 = ln_g + (n * 3 + 0) * 64;     L.be0 = ln_b + (n * 3 + 0) * 64;
  L.g1 = ln_g + (n * 3 + 1) * 64;     L.be1 = ln_b + (n * 3 + 1) * 64;
  L.g2 = ln_g + (n * 3 + 2) * 64;     L.be2 = ln_b + (n * 3 + 2) * 64;
  L.cab1_r = ca_b[(n * 4 + 1) * 64 + lane];
  L.cab2_r = ca_b[(n * 4 + 2) * 64 + lane];
  L.cs1_r = cs_g[(n * 2 + 0) * 64 + lane];
  L.cs2_r = cs_g[(n * 2 + 1) * 64 + lane];
}

// One wave, one row. K/V row stride ks (65 = padded LDS, 64 = ws global).
__device__ float transformer_row(int lane, int t, float x, float q,
                                 const float* Kb, const float* Vb, int ks,
                                 const float* wv, float* xb, float* pb,
                                 const LayerR& P) {
  const float ISQ8 = 0.35355339059327373f;  // 1/sqrt(8)
  // ---- scores: lane = k ----
  xb[lane] = q;
  asm volatile("s_waitcnt lgkmcnt(0)" ::: "memory");
  float a[8] = {0.f, 0.f, 0.f, 0.f, 0.f, 0.f, 0.f, 0.f};
  const float* Krow = Kb + lane * ks;
  const float4* xq4 = (const float4*)xb;
#pragma unroll
  for (int i = 0; i < 16; ++i) {
    float4 xc = xq4[i];
    a[i >> 1] = fmaf(xc.x, Krow[4 * i + 0], a[i >> 1]);
    a[i >> 1] = fmaf(xc.y, Krow[4 * i + 1], a[i >> 1]);
    a[i >> 1] = fmaf(xc.z, Krow[4 * i + 2], a[i >> 1]);
    a[i >> 1] = fmaf(xc.w, Krow[4 * i + 3], a[i >> 1]);
  }
  const bool act = lane < t;
  float m[8];
#pragma unroll
  for (int h = 0; h < 8; ++h) { a[h] = act ? a[h] * ISQ8 : NEG_INF; m[h] = a[h]; }
#pragma unroll
  for (int msk = 1; msk < 64; msk <<= 1) {
#pragma unroll
    for (int h = 0; h < 8; ++h) m[h] = fmaxf(m[h], __shfl_xor(m[h], msk, 64));
  }
  float l[8];
#pragma unroll
  for (int h = 0; h < 8; ++h) { a[h] = act ? expf(a[h] - m[h]) : 0.f; l[h] = a[h]; }
#pragma unroll
  for (int msk = 1; msk < 64; msk <<= 1) {
#pragma unroll
    for (int h = 0; h < 8; ++h) l[h] += __shfl_xor(l[h], msk, 64);
  }
#pragma unroll
  for (int h = 0; h < 8; ++h) pb[h * 64 + lane] = a[h] / l[h];
  asm volatile("s_waitcnt lgkmcnt(0)" ::: "memory");
  // ---- PV: lane = e ----
  const float* pr = pb + (lane >> 3) * 64;
  float attn = 0.f;
  for (int k = 0; k < t; ++k) attn = fmaf(pr[k], Vb[k * ks + lane], attn);

  float y1 = ln64(x + proj_lds(attn, xb, P.saW3, P.sab3, lane), P.g0, P.be0, lane);
  float qc = proj_lds(y1, xb, P.caW0, P.cab0, lane);
  float pa = red8(qc * P.cs1_r);
  float pc = red8(qc * P.cab1_r);
  const float4* wv4 = (const float4*)wv;
  float mc = NEG_INF;
#pragma unroll
  for (int i = 0; i < 16; ++i) {
    float4 wq = wv4[i];
    int k = 4 * i;
    if (k + 0 < t) mc = fmaxf(mc, fmaf(pa, wq.x, pc));
    if (k + 1 < t) mc = fmaxf(mc, fmaf(pa, wq.y, pc));
    if (k + 2 < t) mc = fmaxf(mc, fmaf(pa, wq.z, pc));
    if (k + 3 < t) mc = fmaxf(mc, fmaf(pa, wq.w, pc));
  }
  float lc = 0.f, z = 0.f;
#pragma unroll
  for (int i = 0; i < 16; ++i) {
    float4 wq = wv4[i];
    int k = 4 * i;
    float wk[4] = {wq.x, wq.y, wq.z, wq.w};
#pragma unroll
    for (int j = 0; j < 4; ++j) {
      if (k + j < t) {
        float raw = fmaf(pa, wk[j], pc);
        float pw = expf((raw - mc) * ISQ8);
        lc += pw;
        z = fmaf(pw, wk[j], z);
      }
    }
  }
  float oc = fmaf(z / lc, P.cs2_r, P.cab2_r);
  float y2 = ln64(y1 + proj_lds(oc, xb, P.caW3, P.cab3, lane), P.g1, P.be1, lane);
  float f = fmaxf(proj_lds(y2, xb, P.ffW1, P.ffb1, lane), 0.f);
  float y3 = ln64(y2 + proj_lds(f, xb, P.ffW2, P.ffb2, lane), P.g2, P.be2, lane);
  return y3;
}

// ======== init: 63 blocks. Block 0: wv, cs, seed row 0. Blocks 1..62: one pe row each ========
__global__ __launch_bounds__(1024) void init_kernel(
    const float* __restrict__ noise, const float* __restrict__ lin_W,
    const float* __restrict__ lin_b, const float* __restrict__ sa_W,
    const float* __restrict__ sa_b, const float* __restrict__ ca_W,
    const float* __restrict__ emb, const int* __restrict__ start_id,
    float* __restrict__ wsf) {
  const int tid = threadIdx.x, lane = tid & 63, wvid = tid >> 6;
  const int blk = blockIdx.x;
  __shared__ float xbuf[16 * 64];
  float* myxb = xbuf + wvid * 64;

  if (blk > 0) {  // pe row t = blk (rows 1..62)
    if (tid < 64) {
      int t = blk, e = tid;
      double ang = (double)t / pow(10000.0, (double)(e & 62) / 64.0);
      wsf[WS_PE + t * 64 + e] = (e & 1) ? (float)cos(ang) : (float)sin(ang);
    }
    return;
  }
  if (wvid < 8) {
    int b = wvid;
    float nz = noise[b * 64 + lane];
    float t1 = proj_lds(nz, myxb, lin_W, lin_b, lane);
    wsf[WS_WV + b * 64 + lane] = proj_lds(t1, myxb, lin_W + 4096, lin_b + 64, lane);
  } else if (wvid < 12) {
    int w = wvid - 8, n = w >> 1, which = w & 1;
    float c = 0.f;
    for (int e = 0; e < 64; ++e) c += ca_W[(n * 4 + 1 + which) * 4096 + e * 64 + lane];
    wsf[WS_CS + w * 64 + lane] = c;
  } else {
    for (int b = (wvid - 12) * 2; b <= (wvid - 12) * 2 + 1; ++b) {
      float y0 = emb[start_id[0] * 64 + lane] + ((lane & 1) ? 1.0f : 0.0f);
      float q0 = proj_lds(y0, myxb, sa_W, sa_b, lane);
      float k0 = proj_lds(y0, myxb, sa_W + 4096, sa_b + 64, lane);
      float v0 = proj_lds(y0, myxb, sa_W + 2 * 4096, sa_b + 128, lane);
      wsf[WS_X1 + b * 4096 + lane] = y0;
      wsf[WS_Q1 + b * 4096 + lane] = q0;
      wsf[WS_K1 + b * 4096 + lane] = k0;
      wsf[WS_V1 + b * 4096 + lane] = v0;
    }
  }
}

// ========= trans step t: 8 blocks (1/batch), l1 (<=4 rows/wave serial) + fused l2 =========
// t in [1,64]. t>=2: A-phase reduce stats(t-1) -> MS/argmax; build row t-1.
// t<=63: layer-1 all rows (K2/V2 straight to LDS), then layer-2 on wave 0 -> tokf.
__global__ __launch_bounds__(1024) void trans_kernel(
    const float* __restrict__ sa_W, const float* __restrict__ sa_b,
    const float* __restrict__ ca_W, const float* __restrict__ ca_b,
    const float* __restrict__ ff_W1, const float* __restrict__ ff_b1,
    const float* __restrict__ ff_W2, const float* __restrict__ ff_b2,
    const float* __restrict__ ln_g, const float* __restrict__ ln_b,
    const float* __restrict__ emb, float* __restrict__ wsf, int t) {
  const int tid = threadIdx.x, lane = tid & 63, wvid = tid >> 6;
  const int b = blockIdx.x;
  __shared__ float lds[38144];          // 152576 B
  float* sW   = lds;                    // 3 x 4096: saW3(n0), caW0(n0), caW3(n0)
  float* K1l  = lds + 12288;            // 63 rows stride 65
  float* V1l  = lds + 16384;
  float* K2l  = lds + 20480;
  float* V2l  = lds + 24576;
  float* wvl  = lds + 28672;            // (64)
  float* ynew = lds + 28736;
  float* qnew = lds + 28800;
  float* x2s  = lds + 28864;
  float* xbuf = lds + 28928;            // 16 x 64
  float* pbuf = lds + 29952;            // 16 x 512
  float* myxb = xbuf + wvid * 64;
  float* mypb = pbuf + wvid * 512;

  if (t <= 63) {
    // ---- stage layer-0 weights (3 x 1024 float4, one per thread) ----
    float4* d = (float4*)sW;
    d[tid]        = ((const float4*)(sa_W + 3 * 4096))[tid];
    d[1024 + tid] = ((const float4*)(ca_W))[tid];
    d[2048 + tid] = ((const float4*)(ca_W + 3 * 4096))[tid];
    // ---- stage K1/V1 rows 0..t-2 (t>=2) or row 0 (t==1) ----
    int upto = (t >= 2) ? t - 1 : t;
    for (int r = wvid; r < upto; r += 16) {
      K1l[r * 65 + lane] = wsf[WS_K1 + b * 4096 + r * 64 + lane];
      V1l[r * 65 + lane] = wsf[WS_V1 + b * 4096 + r * 64 + lane];
    }
    if (wvid == 1) wvl[lane] = wsf[WS_WV + b * 64 + lane];
  }

  // ---- A-phase (wave 0): reduce vocab stats(t-1); build row t-1 ----
  if (t >= 2 && wvid == 0) {
    const float* smp = wsf + WS_SM + b * 128;
    const float* ssp = wsf + WS_SS + b * 128;
    const int*   sip = (const int*)(wsf + WS_SI) + b * 128;
    float mA = smp[lane];
    float sA = ssp[lane];
    int   iA = sip[lane];
    const bool a2 = (64 + lane) < NVB;
    float mB = a2 ? smp[64 + lane] : NEG_INF;
    float sB = a2 ? ssp[64 + lane] : 0.f;
    int   iB = a2 ? sip[64 + lane] : 0x7fffffff;
    float mg = mA; int ig = iA;
    if (mB > mg || (mB == mg && iB < ig)) { mg = mB; ig = iB; }
#pragma unroll
    for (int msk = 1; msk < 64; msk <<= 1) {
      float om = __shfl_xor(mg, msk, 64);
      int oi = __shfl_xor(ig, msk, 64);
      if (om > mg || (om == mg && oi < ig)) { mg = om; ig = oi; }
    }
    float part = sA * expf(mA - mg) + (a2 ? sB * expf(mB - mg) : 0.f);
    float S = wsum64(part);
    if (lane == 0) { wsf[WS_MS + b * 2] = mg; wsf[WS_MS + b * 2 + 1] = S; }
    if (t <= 63) {
      float y = emb[ig * 64 + lane] + wsf[WS_PE + (t - 1) * 64 + lane];
      float qn = proj_lds(y, myxb, sa_W, sa_b, lane);
      float kn = proj_lds(y, myxb, sa_W + 4096, sa_b + 64, lane);
      float vn = proj_lds(y, myxb, sa_W + 2 * 4096, sa_b + 128, lane);
      K1l[(t - 1) * 65 + lane] = kn;
      V1l[(t - 1) * 65 + lane] = vn;
      ynew[lane] = y; qnew[lane] = qn;
      wsf[WS_X1 + b * 4096 + (t - 1) * 64 + lane] = y;
      wsf[WS_Q1 + b * 4096 + (t - 1) * 64 + lane] = qn;
      wsf[WS_K1 + b * 4096 + (t - 1) * 64 + lane] = kn;
      wsf[WS_V1 + b * 4096 + (t - 1) * 64 + lane] = vn;
    }
  }
  __syncthreads();
  if (t > 63) return;  // t=64: reduce-only launch

  // ---- layer-1: up to 4 rows per wave (serial slots), K2/V2 straight to LDS ----
  LayerR L0;
  build_layer_s(L0, 0, lane, sW, sa_b, ca_b, ff_W1, ff_b1, ff_W2, ff_b2,
                ln_g, ln_b, wsf + WS_CS);
#pragma unroll
  for (int j = 0; j < 4; ++j) {
    const int row = wvid + 16 * j;
    if (row < t) {
      float x_r, q_r;
      if (t >= 2 && row == t - 1) { x_r = ynew[lane]; q_r = qnew[lane]; }
      else {
        x_r = wsf[WS_X1 + b * 4096 + row * 64 + lane];
        q_r = wsf[WS_Q1 + b * 4096 + row * 64 + lane];
      }
      float out = transformer_row(lane, t, x_r, q_r, K1l, V1l, 65, wvl, myxb, mypb, L0);
      float k2 = proj_lds(out, myxb, sa_W + 5 * 4096, sa_b + 5 * 64, lane);
      float v2 = proj_lds(out, myxb, sa_W + 6 * 4096, sa_b + 6 * 64, lane);
      K2l[row * 65 + lane] = k2;
      V2l[row * 65 + lane] = v2;
      if (row == t - 1) x2s[lane] = out;
    }
  }
  __syncthreads();

  // ---- layer-2 (wave 0), weights global L2-warm -> tokf ----
  if (wvid == 0) {
    LayerR L1;
    build_layer_g(L1, 1, lane, sa_W, sa_b, ca_W, ca_b, ff_W1, ff_b1, ff_W2, ff_b2,
                  ln_g, ln_b, wsf + WS_CS);
    float x2 = x2s[lane];
    float q2 = proj_lds(x2, myxb, sa_W + 4 * 4096, sa_b + 4 * 64, lane);
    float tf = transformer_row(lane, t, x2, q2, K2l, V2l, 65, wvl, myxb, mypb, L1);
    wsf[WS_TOKF + b * 64 + lane] = tf;
  }
}

// =================== vocab step t: 99 blocks x 512 ===================
// t>=2: finalize dout row t-2 (raw logits -> probs) using mS.
// t<=63: logits(t) -> dout row t-1 (raw) + per-block stats.
__global__ __launch_bounds__(512) void vocab_kernel(
    const float* __restrict__ soft_W, const float* __restrict__ soft_b,
    float* __restrict__ wsf, float* __restrict__ dout, int t) {
  const int tid = threadIdx.x, lane = tid & 63, wvid = tid >> 6;  // 8 waves
  const int jb = blockIdx.x;
  const int v = jb * VCOLS + tid;
  const bool valid = v < Vc;
  __shared__ float f2[512];
  __shared__ float sm[64];  __shared__ int si[64];
  __shared__ float ssm[64];
  __shared__ float bmx[8];  __shared__ int bix[8];

  // ---- Phase A: finalize dout row t-2 ----
  if (t >= 2 && valid) {
    long row = (long)(t - 2) * Vc + v;
#pragma unroll
    for (int b2 = 0; b2 < 8; ++b2) {
      float m = wsf[WS_MS + b2 * 2], S = wsf[WS_MS + b2 * 2 + 1];
      long idx = (long)b2 * 63 * Vc + row;
      dout[idx] = expf(dout[idx] - m) / S;
    }
  }
  if (t > 63) return;

  // ---- Phase B: logits(t) ----
  f2[tid] = wsf[WS_TOKF + (tid & 7) * 64 + (tid >> 3)];  // f2[e*8+b]
  __syncthreads();
  float sb = valid ? soft_b[v] : 0.f;
  float lg[8];
#pragma unroll
  for (int b = 0; b < 8; ++b) lg[b] = valid ? sb : NEG_INF;
  if (valid) {
    const float4* f4 = (const float4*)f2;
    const float* col = soft_W + v;
#pragma unroll 8
    for (int e = 0; e < 64; ++e) {
      float wc = col[(long)e * Vc];
      float4 fa = f4[2 * e], fb = f4[2 * e + 1];
      lg[0] = fmaf(fa.x, wc, lg[0]);
      lg[1] = fmaf(fa.y, wc, lg[1]);
      lg[2] = fmaf(fa.z, wc, lg[2]);
      lg[3] = fmaf(fa.w, wc, lg[3]);
      lg[4] = fmaf(fb.x, wc, lg[4]);
      lg[5] = fmaf(fb.y, wc, lg[5]);
      lg[6] = fmaf(fb.z, wc, lg[6]);
      lg[7] = fmaf(fb.w, wc, lg[7]);
    }
  }
#pragma unroll
  for (int b = 0; b < 8; ++b) {
    float m = lg[b]; int ix = valid ? v : 0x7fffffff;
#pragma unroll
    for (int msk = 1; msk < 64; msk <<= 1) {
      float om = __shfl_xor(m, msk, 64);
      int oi = __shfl_xor(ix, msk, 64);
      if (om > m || (om == m && oi < ix)) { m = om; ix = oi; }
    }
    if (lane == 0) { sm[wvid * 8 + b] = m; si[wvid * 8 + b] = ix; }
  }
  __syncthreads();
  if (tid < 8) {
    float m = NEG_INF; int ix = 0x7fffffff;
    for (int wv = 0; wv < 8; ++wv) {
      float om = sm[wv * 8 + tid]; int oi = si[wv * 8 + tid];
      if (om > m || (om == m && oi < ix)) { m = om; ix = oi; }
    }
    bmx[tid] = m; bix[tid] = ix;
  }
  __syncthreads();
#pragma unroll
  for (int b = 0; b < 8; ++b) {
    float c = valid ? expf(lg[b] - bmx[b]) : 0.f;
    float s = wsum64(c);
    if (lane == 0) ssm[wvid * 8 + b] = s;
  }
  __syncthreads();
  if (tid < 8) {
    float s = 0.f;
    for (int wv = 0; wv < 8; ++wv) s += ssm[wv * 8 + tid];
    wsf[WS_SM + tid * 128 + jb] = bmx[tid];
    wsf[WS_SS + tid * 128 + jb] = s;
    ((int*)(wsf + WS_SI))[tid * 128 + jb] = bix[tid];
  }
  // raw logits -> dout row t-1 (scratch; finalized next step)
  if (valid) {
    long row = (long)(t - 1) * Vc + v;
#pragma unroll
    for (int b = 0; b < 8; ++b) dout[(long)b * 63 * Vc + row] = lg[b];
  }
}

extern "C" void kernel_launch(void* const* d_in, const int* in_sizes, int n_in,
                              void* d_out, int out_size, void* d_ws, size_t ws_size,
                              hipStream_t stream) {
  (void)in_sizes; (void)n_in; (void)out_size; (void)ws_size;
  const float* noise  = (const float*)d_in[0];
  const float* lin_W  = (const float*)d_in[1];
  const float* lin_b  = (const float*)d_in[2];
  const float* sa_W   = (const float*)d_in[3];
  const float* sa_b   = (const float*)d_in[4];
  const float* ca_W   = (const float*)d_in[5];
  const float* ca_b   = (const float*)d_in[6];
  const float* ff_W1  = (const float*)d_in[7];
  const float* ff_b1  = (const float*)d_in[8];
  const float* ff_W2  = (const float*)d_in[9];
  const float* ff_b2  = (const float*)d_in[10];
  const float* ln_g   = (const float*)d_in[11];
  const float* ln_b   = (const float*)d_in[12];
  const float* emb    = (const float*)d_in[13];
  const float* soft_W = (const float*)d_in[14];
  const float* soft_b = (const float*)d_in[15];
  const int*   start  = (const int*)d_in[16];
  float* dout = (float*)d_out;
  float* wsf  = (float*)d_ws;

  init_kernel<<<63, 1024, 0, stream>>>(noise, lin_W, lin_b, sa_W, sa_b, ca_W,
                                       emb, start, wsf);
  for (int t = 1; t <= 63; ++t) {
    trans_kernel<<<NB, 1024, 0, stream>>>(sa_W, sa_b, ca_W, ca_b, ff_W1, ff_b1,
                                          ff_W2, ff_b2, ln_g, ln_b, emb, wsf, t);
    vocab_kernel<<<NVB, 512, 0, stream>>>(soft_W, soft_b, wsf, dout, t);
  }
  trans_kernel<<<NB, 1024, 0, stream>>>(sa_W, sa_b, ca_W, ca_b, ff_W1, ff_b1,
                                        ff_W2, ff_b2, ln_g, ln_b, emb, wsf, 64);
  vocab_kernel<<<NVB, 512, 0, stream>>>(soft_W, soft_b, wsf, dout, 64);
}

// Round 13
// 3975.765 us; speedup vs baseline: 6.4077x; 5.1830x over previous
//
#include <hip/hip_runtime.h>
#include <math.h>

#define Vc 50257
#define NEG_INF (-__builtin_inff())
#define VCOLS 512
#define NVB 99      // 99*512 = 50688 >= 50257
#define NB  8

// ---- workspace float offsets (no flags/atomics; coherence = kernel boundaries) ----
#define WS_PE    0        // [64][64] pe rows (1..62 used)
#define WS_WV    4096     // [8][64]
#define WS_CS    4608     // [2 layers][2][64] column sums of ca_W k/v proj
#define WS_TOKF  4864     // [8][64]
#define WS_MS    5376     // [8][2]
#define WS_X2    5632     // [8][64] layer-1 out of row t-1
#define WS_SM    8192     // stats_m [8][128]
#define WS_SS    9216     // stats_s [8][128]
#define WS_SI    10240    // stats_i [8][128] (int)
#define WS_X1    16384    // [8][64][64]
#define WS_Q1    49152
#define WS_K1    81920
#define WS_V1    114688
#define WS_K2G   147456   // [8][64][64] layer-1 K2 outputs
#define WS_V2G   180224   // end 212992 floats (~852 KB)

// ---------------- wave-level helpers ----------------

__device__ __forceinline__ float wsum64(float v) {
#pragma unroll
  for (int m = 32; m >= 1; m >>= 1) v += __shfl_xor(v, m, 64);
  return v;
}

__device__ __forceinline__ float red8(float v) {
  v += __shfl_xor(v, 1, 64);
  v += __shfl_xor(v, 2, 64);
  v += __shfl_xor(v, 4, 64);
  return v;
}

// out[lane] = bias[lane] + sum_e x[e]*W[e*64+lane]; x broadcast via LDS float4 reads.
// W may live in LDS (staged) or global (L2-warm).
__device__ __forceinline__ float proj_lds(float xv, float* xb,
                                          const float* W,
                                          const float* __restrict__ bias, int lane) {
  xb[lane] = xv;
  asm volatile("s_waitcnt lgkmcnt(0)" ::: "memory");
  float acc = bias[lane];
  const float4* x4 = (const float4*)xb;
#pragma unroll
  for (int i = 0; i < 16; ++i) {
    float4 xc = x4[i];
    acc = fmaf(xc.x, W[(4 * i + 0) * 64 + lane], acc);
    acc = fmaf(xc.y, W[(4 * i + 1) * 64 + lane], acc);
    acc = fmaf(xc.z, W[(4 * i + 2) * 64 + lane], acc);
    acc = fmaf(xc.w, W[(4 * i + 3) * 64 + lane], acc);
  }
  asm volatile("" ::: "memory");
  return acc;
}

__device__ __forceinline__ float ln64(float xv, const float* __restrict__ g,
                                      const float* __restrict__ b, int lane) {
  float mean = wsum64(xv) * 0.015625f;
  float d = xv - mean;
  float var = wsum64(d * d) * 0.015625f;
  float r = 1.0f / sqrtf(var + 1e-5f);
  return d * r * g[lane] + b[lane];
}

struct LayerR {
  const float *saW3, *sab3, *caW0, *cab0, *caW3, *cab3,
              *ffW1, *ffb1, *ffW2, *ffb2, *g0, *be0, *g1, *be1, *g2, *be2;
  float cs1_r, cs2_r, cab1_r, cab2_r;
};

// saW3/caW0/caW3 from LDS-staged copies; rest global.
__device__ __forceinline__ void build_layer_s(LayerR& L, int n, int lane,
    const float* sWl, const float* sa_b, const float* ca_b,
    const float* ff_W1, const float* ff_b1, const float* ff_W2, const float* ff_b2,
    const float* ln_g, const float* ln_b, const float* cs_g) {
  L.saW3 = sWl;              L.sab3 = sa_b + (n * 4 + 3) * 64;
  L.caW0 = sWl + 4096;       L.cab0 = ca_b + (n * 4 + 0) * 64;
  L.caW3 = sWl + 2 * 4096;   L.cab3 = ca_b + (n * 4 + 3) * 64;
  L.ffW1 = ff_W1 + n * 4096; L.ffb1 = ff_b1 + n * 64;
  L.ffW2 = ff_W2 + n * 4096; L.ffb2 = ff_b2 + n * 64;
  L.g0 = ln_g + (n * 3 + 0) * 64;  L.be0 = ln_b + (n * 3 + 0) * 64;
  L.g1 = ln_g + (n * 3 + 1) * 64;  L.be1 = ln_b + (n * 3 + 1) * 64;
  L.g2 = ln_g + (n * 3 + 2) * 64;  L.be2 = ln_b + (n * 3 + 2) * 64;
  L.cab1_r = ca_b[(n * 4 + 1) * 64 + lane];
  L.cab2_r = ca_b[(n * 4 + 2) * 64 + lane];
  L.cs1_r = cs_g[(n * 2 + 0) * 64 + lane];
  L.cs2_r = cs_g[(n * 2 + 1) * 64 + lane];
}

// all-global version (weights L2-warm) — used by the l2 kernel
__device__ __forceinline__ void build_layer_g(LayerR& L, int n, int lane,
    const float* sWl, const float* sa_b, const float* ca_b,
    const float* ff_W1, const float* ff_b1, const float* ff_W2, const float* ff_b2,
    const float* ln_g, const float* ln_b, const float* cs_g) {
  L.saW3 = sWl;              L.sab3 = sa_b + (n * 4 + 3) * 64;
  L.caW0 = sWl + 4096;       L.cab0 = ca_b + (n * 4 + 0) * 64;
  L.caW3 = sWl + 2 * 4096;   L.cab3 = ca_b + (n * 4 + 3) * 64;
  L.ffW1 = ff_W1 + n * 4096; L.ffb1 = ff_b1 + n * 64;
  L.ffW2 = ff_W2 + n * 4096; L.ffb2 = ff_b2 + n * 64;
  L.g0 = ln_g + (n * 3 + 0) * 64;  L.be0 = ln_b + (n * 3 + 0) * 64;
  L.g1 = ln_g + (n * 3 + 1) * 64;  L.be1 = ln_b + (n * 3 + 1) * 64;
  L.g2 = ln_g + (n * 3 + 2) * 64;  L.be2 = ln_b + (n * 3 + 2) * 64;
  L.cab1_r = ca_b[(n * 4 + 1) * 64 + lane];
  L.cab2_r = ca_b[(n * 4 + 2) * 64 + lane];
  L.cs1_r = cs_g[(n * 2 + 0) * 64 + lane];
  L.cs2_r = cs_g[(n * 2 + 1) * 64 + lane];
}

// One wave, one row. K/V in LDS with row stride 65.
__device__ float transformer_row(int lane, int t, float x, float q,
                                 const float* Kb, const float* Vb,
                                 const float* wv, float* xb, float* pb,
                                 const LayerR& P) {
  const float ISQ8 = 0.35355339059327373f;  // 1/sqrt(8)
  // ---- scores: lane = k ----
  xb[lane] = q;
  asm volatile("s_waitcnt lgkmcnt(0)" ::: "memory");
  float a[8] = {0.f, 0.f, 0.f, 0.f, 0.f, 0.f, 0.f, 0.f};
  const float* Krow = Kb + lane * 65;
  const float4* xq4 = (const float4*)xb;
#pragma unroll
  for (int i = 0; i < 16; ++i) {
    float4 xc = xq4[i];
    a[i >> 1] = fmaf(xc.x, Krow[4 * i + 0], a[i >> 1]);
    a[i >> 1] = fmaf(xc.y, Krow[4 * i + 1], a[i >> 1]);
    a[i >> 1] = fmaf(xc.z, Krow[4 * i + 2], a[i >> 1]);
    a[i >> 1] = fmaf(xc.w, Krow[4 * i + 3], a[i >> 1]);
  }
  const bool act = lane < t;
  float m[8];
#pragma unroll
  for (int h = 0; h < 8; ++h) { a[h] = act ? a[h] * ISQ8 : NEG_INF; m[h] = a[h]; }
#pragma unroll
  for (int msk = 1; msk < 64; msk <<= 1) {
#pragma unroll
    for (int h = 0; h < 8; ++h) m[h] = fmaxf(m[h], __shfl_xor(m[h], msk, 64));
  }
  float l[8];
#pragma unroll
  for (int h = 0; h < 8; ++h) { a[h] = act ? expf(a[h] - m[h]) : 0.f; l[h] = a[h]; }
#pragma unroll
  for (int msk = 1; msk < 64; msk <<= 1) {
#pragma unroll
    for (int h = 0; h < 8; ++h) l[h] += __shfl_xor(l[h], msk, 64);
  }
#pragma unroll
  for (int h = 0; h < 8; ++h) pb[h * 64 + lane] = a[h] / l[h];
  asm volatile("s_waitcnt lgkmcnt(0)" ::: "memory");
  // ---- PV: lane = e ----
  const float* pr = pb + (lane >> 3) * 64;
  float attn = 0.f;
  for (int k = 0; k < t; ++k) attn = fmaf(pr[k], Vb[k * 65 + lane], attn);

  float y1 = ln64(x + proj_lds(attn, xb, P.saW3, P.sab3, lane), P.g0, P.be0, lane);
  float qc = proj_lds(y1, xb, P.caW0, P.cab0, lane);
  float pa = red8(qc * P.cs1_r);
  float pc = red8(qc * P.cab1_r);
  const float4* wv4 = (const float4*)wv;
  float mc = NEG_INF;
#pragma unroll
  for (int i = 0; i < 16; ++i) {
    float4 wq = wv4[i];
    int k = 4 * i;
    if (k + 0 < t) mc = fmaxf(mc, fmaf(pa, wq.x, pc));
    if (k + 1 < t) mc = fmaxf(mc, fmaf(pa, wq.y, pc));
    if (k + 2 < t) mc = fmaxf(mc, fmaf(pa, wq.z, pc));
    if (k + 3 < t) mc = fmaxf(mc, fmaf(pa, wq.w, pc));
  }
  float lc = 0.f, z = 0.f;
#pragma unroll
  for (int i = 0; i < 16; ++i) {
    float4 wq = wv4[i];
    int k = 4 * i;
    float wk[4] = {wq.x, wq.y, wq.z, wq.w};
#pragma unroll
    for (int j = 0; j < 4; ++j) {
      if (k + j < t) {
        float raw = fmaf(pa, wk[j], pc);
        float pw = expf((raw - mc) * ISQ8);
        lc += pw;
        z = fmaf(pw, wk[j], z);
      }
    }
  }
  float oc = fmaf(z / lc, P.cs2_r, P.cab2_r);
  float y2 = ln64(y1 + proj_lds(oc, xb, P.caW3, P.cab3, lane), P.g1, P.be1, lane);
  float f = fmaxf(proj_lds(y2, xb, P.ffW1, P.ffb1, lane), 0.f);
  float y3 = ln64(y2 + proj_lds(f, xb, P.ffW2, P.ffb2, lane), P.g2, P.be2, lane);
  return y3;
}

// =================== init: pe table, w-vector, ca column sums, seed row 0 ===================
__global__ __launch_bounds__(1024) void init_kernel(
    const float* __restrict__ noise, const float* __restrict__ lin_W,
    const float* __restrict__ lin_b, const float* __restrict__ sa_W,
    const float* __restrict__ sa_b, const float* __restrict__ ca_W,
    const float* __restrict__ emb, const int* __restrict__ start_id,
    float* __restrict__ wsf) {
  const int tid = threadIdx.x, lane = tid & 63, wvid = tid >> 6;
  __shared__ float xbuf[16 * 64];
  float* myxb = xbuf + wvid * 64;

  for (int i = tid; i < 62 * 64; i += 1024) {
    int t = 1 + (i >> 6), e = i & 63;
    double ang = (double)t / pow(10000.0, (double)(e & 62) / 64.0);
    wsf[WS_PE + t * 64 + e] = (e & 1) ? (float)cos(ang) : (float)sin(ang);
  }
  if (wvid < 8) {
    int b = wvid;
    float nz = noise[b * 64 + lane];
    float t1 = proj_lds(nz, myxb, lin_W, lin_b, lane);
    wsf[WS_WV + b * 64 + lane] = proj_lds(t1, myxb, lin_W + 4096, lin_b + 64, lane);
  } else if (wvid < 12) {
    int w = wvid - 8, n = w >> 1, which = w & 1;
    float c = 0.f;
    for (int e = 0; e < 64; ++e) c += ca_W[(n * 4 + 1 + which) * 4096 + e * 64 + lane];
    wsf[WS_CS + w * 64 + lane] = c;
  } else {
    for (int b = (wvid - 12) * 2; b <= (wvid - 12) * 2 + 1; ++b) {
      float y0 = emb[start_id[0] * 64 + lane] + ((lane & 1) ? 1.0f : 0.0f);
      float q0 = proj_lds(y0, myxb, sa_W, sa_b, lane);
      float k0 = proj_lds(y0, myxb, sa_W + 4096, sa_b + 64, lane);
      float v0 = proj_lds(y0, myxb, sa_W + 2 * 4096, sa_b + 128, lane);
      wsf[WS_X1 + b * 4096 + lane] = y0;
      wsf[WS_Q1 + b * 4096 + lane] = q0;
      wsf[WS_K1 + b * 4096 + lane] = k0;
      wsf[WS_V1 + b * 4096 + lane] = v0;
    }
  }
}

// =================== layer-1 step t: 32 blocks (4/batch), 1 row/wave ===================
// Each block: stage L0 weights->LDS, stage K1/V1, redundant A-phase
// (reduce stats(t-1) -> mS,argmax; build row t-1), then layer-1 rows.
__global__ __launch_bounds__(1024) void l1_kernel(
    const float* __restrict__ sa_W, const float* __restrict__ sa_b,
    const float* __restrict__ ca_W, const float* __restrict__ ca_b,
    const float* __restrict__ ff_W1, const float* __restrict__ ff_b1,
    const float* __restrict__ ff_W2, const float* __restrict__ ff_b2,
    const float* __restrict__ ln_g, const float* __restrict__ ln_b,
    const float* __restrict__ emb, float* __restrict__ wsf, int t) {
  const int tid = threadIdx.x, lane = tid & 63, wvid = tid >> 6;
  const int b = blockIdx.x >> 2, sb = blockIdx.x & 3;
  __shared__ float lds[29888];          // 119552 B
  float* sW   = lds;                    // 3 x 4096 (saW3, caW0, caW3)
  float* K1l  = lds + 12288;            // 63 rows stride 65
  float* V1l  = lds + 16384;
  float* wvl  = lds + 20480;
  float* ynew = lds + 20544;
  float* qnew = lds + 20608;
  float* xbuf = lds + 20672;            // 16 x 64
  float* pbuf = lds + 21696;            // 16 x 512
  float* myxb = xbuf + wvid * 64;
  float* mypb = pbuf + wvid * 512;

  if (t <= 63) {
    // ---- stage weights (3 x 1024 float4, one per thread) ----
    float4* d = (float4*)sW;
    d[tid]        = ((const float4*)(sa_W + 3 * 4096))[tid];
    d[1024 + tid] = ((const float4*)(ca_W))[tid];
    d[2048 + tid] = ((const float4*)(ca_W + 3 * 4096))[tid];
    // ---- stage K1/V1 rows 0..t-2 (t>=2) or row 0 (t==1) ----
    int upto = (t >= 2) ? t - 1 : t;
    for (int r = wvid; r < upto; r += 16) {
      K1l[r * 65 + lane] = wsf[WS_K1 + b * 4096 + r * 64 + lane];
      V1l[r * 65 + lane] = wsf[WS_V1 + b * 4096 + r * 64 + lane];
    }
    if (wvid == 1) wvl[lane] = wsf[WS_WV + b * 64 + lane];
  }

  // ---- A-phase (wave 0): reduce vocab stats(t-1); build row t-1 ----
  if (t >= 2 && wvid == 0) {
    const float* smp = wsf + WS_SM + b * 128;
    const float* ssp = wsf + WS_SS + b * 128;
    const int*   sip = (const int*)(wsf + WS_SI) + b * 128;
    float mA = smp[lane];
    float sA = ssp[lane];
    int   iA = sip[lane];
    const bool a2 = (64 + lane) < NVB;
    float mB = a2 ? smp[64 + lane] : NEG_INF;
    float sB = a2 ? ssp[64 + lane] : 0.f;
    int   iB = a2 ? sip[64 + lane] : 0x7fffffff;
    float mg = mA; int ig = iA;
    if (mB > mg || (mB == mg && iB < ig)) { mg = mB; ig = iB; }
#pragma unroll
    for (int msk = 1; msk < 64; msk <<= 1) {
      float om = __shfl_xor(mg, msk, 64);
      int oi = __shfl_xor(ig, msk, 64);
      if (om > mg || (om == mg && oi < ig)) { mg = om; ig = oi; }
    }
    float part = sA * expf(mA - mg) + (a2 ? sB * expf(mB - mg) : 0.f);
    float S = wsum64(part);
    if (lane == 0) { wsf[WS_MS + b * 2] = mg; wsf[WS_MS + b * 2 + 1] = S; }
    if (t <= 63) {
      float y = emb[ig * 64 + lane] + wsf[WS_PE + (t - 1) * 64 + lane];
      float qn = proj_lds(y, myxb, sa_W, sa_b, lane);
      float kn = proj_lds(y, myxb, sa_W + 4096, sa_b + 64, lane);
      float vn = proj_lds(y, myxb, sa_W + 2 * 4096, sa_b + 128, lane);
      K1l[(t - 1) * 65 + lane] = kn;
      V1l[(t - 1) * 65 + lane] = vn;
      ynew[lane] = y; qnew[lane] = qn;
      if (sb == ((t - 1) >> 4)) {  // owner block persists row t-1 to ws
        wsf[WS_X1 + b * 4096 + (t - 1) * 64 + lane] = y;
        wsf[WS_Q1 + b * 4096 + (t - 1) * 64 + lane] = qn;
        wsf[WS_K1 + b * 4096 + (t - 1) * 64 + lane] = kn;
        wsf[WS_V1 + b * 4096 + (t - 1) * 64 + lane] = vn;
      }
    }
  }
  __syncthreads();
  if (t > 63) return;  // t=64: reduce-only launch

  // ---- layer-1: one row per wave ----
  const int row = sb * 16 + wvid;
  if (row < t) {
    float x_r, q_r;
    if (t >= 2 && row == t - 1) { x_r = ynew[lane]; q_r = qnew[lane]; }
    else {
      x_r = wsf[WS_X1 + b * 4096 + row * 64 + lane];
      q_r = wsf[WS_Q1 + b * 4096 + row * 64 + lane];
    }
    LayerR L0;
    build_layer_s(L0, 0, lane, sW, sa_b, ca_b, ff_W1, ff_b1, ff_W2, ff_b2,
                  ln_g, ln_b, wsf + WS_CS);
    float out = transformer_row(lane, t, x_r, q_r, K1l, V1l, wvl, myxb, mypb, L0);
    float k2 = proj_lds(out, myxb, sa_W + 5 * 4096, sa_b + 5 * 64, lane);
    float v2 = proj_lds(out, myxb, sa_W + 6 * 4096, sa_b + 6 * 64, lane);
    wsf[WS_K2G + b * 4096 + row * 64 + lane] = k2;
    wsf[WS_V2G + b * 4096 + row * 64 + lane] = v2;
    if (row == t - 1) wsf[WS_X2 + b * 64 + lane] = out;
  }
}

// =================== layer-2 step t: 8 blocks ===================
__global__ __launch_bounds__(1024) void l2_kernel(
    const float* __restrict__ sa_W, const float* __restrict__ sa_b,
    const float* __restrict__ ca_W, const float* __restrict__ ca_b,
    const float* __restrict__ ff_W1, const float* __restrict__ ff_b1,
    const float* __restrict__ ff_W2, const float* __restrict__ ff_b2,
    const float* __restrict__ ln_g, const float* __restrict__ ln_b,
    float* __restrict__ wsf, int t) {
  const int tid = threadIdx.x, lane = tid & 63, wvid = tid >> 6;
  const int b = blockIdx.x;
  __shared__ float lds[22592];          // 90368 B
  float* sW   = lds;                    // 3 x 4096 (saW3 n1, caW0 n1, caW3 n1)
  float* K2l  = lds + 12288;
  float* V2l  = lds + 16384;
  float* wvl  = lds + 20480;
  float* xbuf = lds + 20544;            // wave0 only needs 64; keep 16x64
  float* pbuf = lds + 21568;            // 512 (wave 0)
  float* myxb = xbuf + wvid * 64;

  float4* d = (float4*)sW;
  d[tid]        = ((const float4*)(sa_W + 7 * 4096))[tid];
  d[1024 + tid] = ((const float4*)(ca_W + 4 * 4096))[tid];
  d[2048 + tid] = ((const float4*)(ca_W + 7 * 4096))[tid];
  for (int r = wvid; r < t; r += 16) {
    K2l[r * 65 + lane] = wsf[WS_K2G + b * 4096 + r * 64 + lane];
    V2l[r * 65 + lane] = wsf[WS_V2G + b * 4096 + r * 64 + lane];
  }
  if (wvid == 1) wvl[lane] = wsf[WS_WV + b * 64 + lane];
  __syncthreads();

  if (wvid == 0) {
    LayerR L1;
    build_layer_g(L1, 1, lane, sW, sa_b, ca_b, ff_W1, ff_b1, ff_W2, ff_b2,
                  ln_g, ln_b, wsf + WS_CS);
    float x2 = wsf[WS_X2 + b * 64 + lane];
    float q2 = proj_lds(x2, myxb, sa_W + 4 * 4096, sa_b + 4 * 64, lane);
    float tf = transformer_row(lane, t, x2, q2, K2l, V2l, wvl, myxb, pbuf, L1);
    wsf[WS_TOKF + b * 64 + lane] = tf;
  }
}

// =================== vocab step t: 99 blocks x 512 ===================
// t>=2: finalize dout row t-2 (raw logits -> probs) using mS.
// t<=63: logits(t) -> dout row t-1 (raw) + per-block stats.
__global__ __launch_bounds__(512) void vocab_kernel(
    const float* __restrict__ soft_W, const float* __restrict__ soft_b,
    float* __restrict__ wsf, float* __restrict__ dout, int t) {
  const int tid = threadIdx.x, lane = tid & 63, wvid = tid >> 6;  // 8 waves
  const int jb = blockIdx.x;
  const int v = jb * VCOLS + tid;
  const bool valid = v < Vc;
  __shared__ float f2[512];
  __shared__ float sm[64];  __shared__ int si[64];
  __shared__ float ssm[64];
  __shared__ float bmx[8];  __shared__ int bix[8];

  if (t >= 2 && valid) {
    long row = (long)(t - 2) * Vc + v;
#pragma unroll
    for (int b2 = 0; b2 < 8; ++b2) {
      float m = wsf[WS_MS + b2 * 2], S = wsf[WS_MS + b2 * 2 + 1];
      long idx = (long)b2 * 63 * Vc + row;
      dout[idx] = expf(dout[idx] - m) / S;
    }
  }
  if (t > 63) return;

  f2[tid] = wsf[WS_TOKF + (tid & 7) * 64 + (tid >> 3)];  // f2[e*8+b]
  __syncthreads();
  float sb = valid ? soft_b[v] : 0.f;
  float lg[8];
#pragma unroll
  for (int b = 0; b < 8; ++b) lg[b] = valid ? sb : NEG_INF;
  if (valid) {
    const float4* f4 = (const float4*)f2;
    const float* col = soft_W + v;
#pragma unroll 8
    for (int e = 0; e < 64; ++e) {
      float wc = col[(long)e * Vc];
      float4 fa = f4[2 * e], fb = f4[2 * e + 1];
      lg[0] = fmaf(fa.x, wc, lg[0]);
      lg[1] = fmaf(fa.y, wc, lg[1]);
      lg[2] = fmaf(fa.z, wc, lg[2]);
      lg[3] = fmaf(fa.w, wc, lg[3]);
      lg[4] = fmaf(fb.x, wc, lg[4]);
      lg[5] = fmaf(fb.y, wc, lg[5]);
      lg[6] = fmaf(fb.z, wc, lg[6]);
      lg[7] = fmaf(fb.w, wc, lg[7]);
    }
  }
#pragma unroll
  for (int b = 0; b < 8; ++b) {
    float m = lg[b]; int ix = valid ? v : 0x7fffffff;
#pragma unroll
    for (int msk = 1; msk < 64; msk <<= 1) {
      float om = __shfl_xor(m, msk, 64);
      int oi = __shfl_xor(ix, msk, 64);
      if (om > m || (om == m && oi < ix)) { m = om; ix = oi; }
    }
    if (lane == 0) { sm[wvid * 8 + b] = m; si[wvid * 8 + b] = ix; }
  }
  __syncthreads();
  if (tid < 8) {
    float m = NEG_INF; int ix = 0x7fffffff;
    for (int wv = 0; wv < 8; ++wv) {
      float om = sm[wv * 8 + tid]; int oi = si[wv * 8 + tid];
      if (om > m || (om == m && oi < ix)) { m = om; ix = oi; }
    }
    bmx[tid] = m; bix[tid] = ix;
  }
  __syncthreads();
#pragma unroll
  for (int b = 0; b < 8; ++b) {
    float c = valid ? expf(lg[b] - bmx[b]) : 0.f;
    float s = wsum64(c);
    if (lane == 0) ssm[wvid * 8 + b] = s;
  }
  __syncthreads();
  if (tid < 8) {
    float s = 0.f;
    for (int wv = 0; wv < 8; ++wv) s += ssm[wv * 8 + tid];
    wsf[WS_SM + tid * 128 + jb] = bmx[tid];
    wsf[WS_SS + tid * 128 + jb] = s;
    ((int*)(wsf + WS_SI))[tid * 128 + jb] = bix[tid];
  }
  if (valid) {
    long row = (long)(t - 1) * Vc + v;
#pragma unroll
    for (int b = 0; b < 8; ++b) dout[(long)b * 63 * Vc + row] = lg[b];
  }
}

extern "C" void kernel_launch(void* const* d_in, const int* in_sizes, int n_in,
                              void* d_out, int out_size, void* d_ws, size_t ws_size,
                              hipStream_t stream) {
  (void)in_sizes; (void)n_in; (void)out_size; (void)ws_size;
  const float* noise  = (const float*)d_in[0];
  const float* lin_W  = (const float*)d_in[1];
  const float* lin_b  = (const float*)d_in[2];
  const float* sa_W   = (const float*)d_in[3];
  const float* sa_b   = (const float*)d_in[4];
  const float* ca_W   = (const float*)d_in[5];
  const float* ca_b   = (const float*)d_in[6];
  const float* ff_W1  = (const float*)d_in[7];
  const float* ff_b1  = (const float*)d_in[8];
  const float* ff_W2  = (const float*)d_in[9];
  const float* ff_b2  = (const float*)d_in[10];
  const float* ln_g   = (const float*)d_in[11];
  const float* ln_b   = (const float*)d_in[12];
  const float* emb    = (const float*)d_in[13];
  const float* soft_W = (const float*)d_in[14];
  const float* soft_b = (const float*)d_in[15];
  const int*   start  = (const int*)d_in[16];
  float* dout = (float*)d_out;
  float* wsf  = (float*)d_ws;

  init_kernel<<<1, 1024, 0, stream>>>(noise, lin_W, lin_b, sa_W, sa_b, ca_W,
                                      emb, start, wsf);
  for (int t = 1; t <= 63; ++t) {
    l1_kernel<<<32, 1024, 0, stream>>>(sa_W, sa_b, ca_W, ca_b, ff_W1, ff_b1,
                                       ff_W2, ff_b2, ln_g, ln_b, emb, wsf, t);
    l2_kernel<<<NB, 1024, 0, stream>>>(sa_W, sa_b, ca_W, ca_b, ff_W1, ff_b1,
                                       ff_W2, ff_b2, ln_g, ln_b, wsf, t);
    vocab_kernel<<<NVB, 512, 0, stream>>>(soft_W, soft_b, wsf, dout, t);
  }
  l1_kernel<<<32, 1024, 0, stream>>>(sa_W, sa_b, ca_W, ca_b, ff_W1, ff_b1,
                                     ff_W2, ff_b2, ln_g, ln_b, emb, wsf, 64);
  vocab_kernel<<<NVB, 512, 0, stream>>>(soft_W, soft_b, wsf, dout, 64);
}